// Round 6
// baseline (237.254 us; speedup 1.0000x reference)
//
#include <hip/hip_runtime.h>

// Causal MHA, B=128 T=256 C=384 H=6 d=64, fp32 in/out.
// prep_w: W->W^T bf16 via LDS tile transpose (Wq pre-scaled by 1/sqrt(C)*log2e). 108 blocks.
// fused: one block per (b,h), 512 thr = 8 waves, 128KB LDS, ONE barrier total.
//   Phase A: QKV projection [256 tok x 192 n'] with ZERO LDS staging and ZERO barriers:
//            A-frags read directly from X fp32 (global, L2-hot: 6 same-b heads/XCD)
//            + cvt_pk to bf16; B-frags read directly from WT bf16 (0.9MB, L2-resident).
//            Waves fully independent -> drift + co-schedule hides all load latency.
//   Epilogue: acc -> Q/K rows, V^T in LDS, XOR bank-swizzled. __syncthreads.
//   Phase B: flash attention from LDS; waves own group pairs {w, 15-w} (5 visits);
//            dual-group interleave; defer-rescale THR=8 (T13); cvt_pk packs (T12).

typedef unsigned short u16;
typedef float f32x4 __attribute__((ext_vector_type(4)));
typedef short s16x8 __attribute__((ext_vector_type(8)));
typedef u16 u16x4 __attribute__((ext_vector_type(4)));

static constexpr int BB = 128;
static constexpr int TT = 256;
static constexpr int CC = 384;
static constexpr int HH = 6;
static constexpr int DD = 64;

// ws layout (u16): WT3 [1152][384]
static constexpr float CSC = 0.07362242194579907f;  // (1/sqrt(384)) * log2(e)

__device__ __forceinline__ u16 f2bf(float f) {
  unsigned u = __float_as_uint(f);
  u += 0x7fffu + ((u >> 16) & 1u);   // RTN-even
  return (u16)(u >> 16);
}

// packed f32 pair -> bf16 pair (RTN-even), single VALU op
__device__ __forceinline__ unsigned cvtpk(float lo, float hi) {
  unsigned r;
  asm("v_cvt_pk_bf16_f32 %0, %1, %2" : "=v"(r) : "v"(lo), "v"(hi));
  return r;
}

__device__ __forceinline__ s16x8 pack4(unsigned a, unsigned b, unsigned c, unsigned d) {
  union { unsigned u[4]; s16x8 v; } t;
  t.u[0] = a; t.u[1] = b; t.u[2] = c; t.u[3] = d;
  return t.v;
}

// ---------- prep_w: W^T via LDS transpose (108 blocks: 3 z x 36 tiles of 64x64) ----------
__global__ void prep_w(const float* __restrict__ Wq, const float* __restrict__ Wk,
                       const float* __restrict__ Wv, u16* __restrict__ ws) {
  __shared__ u16 Lt[64][66];
  int j = blockIdx.x;
  int z = j / 36, t = j % 36, ti = t / 6, tj = t % 6;
  const float* W = (z == 0) ? Wq : (z == 1) ? Wk : Wv;
  const float sc = (z == 0) ? CSC : 1.0f;
  u16* WT = ws + (size_t)z * CC * CC;
  const int rl = threadIdx.x >> 4;
  const int cl = (threadIdx.x & 15) * 4;
#pragma unroll
  for (int it = 0; it < 4; ++it) {
    int r = it * 16 + rl;
    f32x4 v = *(const f32x4*)(W + (size_t)(ti * 64 + r) * CC + tj * 64 + cl);
#pragma unroll
    for (int q = 0; q < 4; ++q) Lt[r][cl + q] = f2bf(v[q] * sc);
  }
  __syncthreads();
#pragma unroll
  for (int it = 0; it < 4; ++it) {
    int n = it * 16 + rl;
    u16x4 o;
#pragma unroll
    for (int q = 0; q < 4; ++q) o[q] = Lt[cl + q][n];
    *(u16x4*)(WT + (size_t)(tj * 64 + n) * CC + ti * 64 + cl) = o;
  }
}

// ---------- fused QKV projection + flash attention ----------
__global__ __launch_bounds__(512, 2) void fused(const float* __restrict__ X,
                                                const u16* __restrict__ ws,
                                                float* __restrict__ out) {
  // XCD clustering: 6 heads of same b share ids congruent mod 8 -> same XCD L2
  const int bid = blockIdx.x;
  const int xc = bid & 7;
  const int g5 = bid >> 3;           // 0..95
  const int b = xc * 16 + g5 / 6;
  const int h = g5 % 6;

  __shared__ u16 Qs[256][64];        // Q rows, XOR-swizzled by (tok&7)<<3
  __shared__ u16 Ks[256][64];        // K rows, XOR-swizzled
  __shared__ u16 VTs[64][256];       // V^T, XOR-swizzled by (d&15)<<3
  __shared__ u16 Ps[8][2048];        // per-wave P^T round-trip (2 groups x [16][64])

  const int tid = threadIdx.x;
  const int lane = tid & 63;
  const int w = tid >> 6;            // 0..7
  const int quad = lane >> 4;
  const int col = lane & 15;

  const int wm = (w >> 1) * 64;      // token quadrant
  const int wn = (w & 1) * 96;       // n' half (Q:0-63 K:64-127 V:128-191)

  const float* Xg = X + (size_t)b * TT * CC;   // [256][384] fp32

  // Per-lane row bases (constant over kt)
  const float* arow[4];
#pragma unroll
  for (int mt = 0; mt < 4; ++mt) arow[mt] = Xg + (size_t)(wm + mt * 16 + col) * CC;
  const u16* brow[6];
#pragma unroll
  for (int nt = 0; nt < 6; ++nt) {
    int gn = wn + nt * 16 + col;               // n' in [0,192)
    brow[nt] = ws + (size_t)((gn >> 6) * CC + h * DD + (gn & 63)) * CC;
  }

  // ---------------- Phase A: barrier-free register GEMM over kt ----------------
  f32x4 acc[4][6] = {};

#pragma unroll
  for (int kt = 0; kt < 6; ++kt) {
    const int d0 = kt * 64 + quad * 8;
    s16x8 af[4][2], bf[6][2];
#pragma unroll
    for (int mt = 0; mt < 4; ++mt)
#pragma unroll
      for (int ks = 0; ks < 2; ++ks) {
        f32x4 x0 = *(const f32x4*)(arow[mt] + d0 + ks * 32);
        f32x4 x1 = *(const f32x4*)(arow[mt] + d0 + ks * 32 + 4);
        af[mt][ks] = pack4(cvtpk(x0[0], x0[1]), cvtpk(x0[2], x0[3]),
                           cvtpk(x1[0], x1[1]), cvtpk(x1[2], x1[3]));
      }
#pragma unroll
    for (int nt = 0; nt < 6; ++nt)
#pragma unroll
      for (int ks = 0; ks < 2; ++ks)
        bf[nt][ks] = *(const s16x8*)(brow[nt] + d0 + ks * 32);

#pragma unroll
    for (int ks = 0; ks < 2; ++ks)
#pragma unroll
      for (int mt = 0; mt < 4; ++mt)
#pragma unroll
        for (int nt = 0; nt < 6; ++nt)
          acc[mt][nt] = __builtin_amdgcn_mfma_f32_16x16x32_bf16(
              af[mt][ks], bf[nt][ks], acc[mt][nt], 0, 0, 0);
  }

  // ------ Epilogue: acc -> Q / K rows, V^T; XOR bank-swizzle ------
  u16* Qb  = &Qs[0][0];
  u16* KsB = &Ks[0][0];
#pragma unroll
  for (int mt = 0; mt < 4; ++mt) {
    int tokb = wm + mt * 16 + quad * 4;
#pragma unroll
    for (int nt = 0; nt < 6; ++nt) {
      int gn = wn + nt * 16 + col;           // class uniform per (w,nt)
      unsigned u01 = cvtpk(acc[mt][nt][0], acc[mt][nt][1]);
      unsigned u23 = cvtpk(acc[mt][nt][2], acc[mt][nt][3]);
      if (gn < 128) {
        u16* dst = (gn < 64) ? Qb : KsB;
        int d = gn & 63;
        dst[(tokb + 0) * 64 + (d ^ (((tokb + 0) & 7) << 3))] = (u16)u01;
        dst[(tokb + 1) * 64 + (d ^ (((tokb + 1) & 7) << 3))] = (u16)(u01 >> 16);
        dst[(tokb + 2) * 64 + (d ^ (((tokb + 2) & 7) << 3))] = (u16)u23;
        dst[(tokb + 3) * 64 + (d ^ (((tokb + 3) & 7) << 3))] = (u16)(u23 >> 16);
      } else {
        int d = gn - 128;
        *(uint2*)((u16*)VTs + d * 256 + (tokb ^ ((d & 15) << 3))) =
            make_uint2(u01, u23);
      }
    }
  }
  __syncthreads();                   // the ONLY block-wide barrier

  // ---------------- Phase B: flash attention from LDS, barrier-free ----------------
  const int g0 = w, g1 = 15 - w;             // this wave's two q-groups
  const int k0max = g0 >> 2, k1max = g1 >> 2;
  const int qq0 = (g0 & 3) * 16 + col;
  const int qq1 = (g1 & 3) * 16 + col;
  u16* PsA = &Ps[w][0];                      // per-wave [16][64] swizzled
  u16* PsB = PsA + 1024;

  s16x8 qf[2][2];
  {
    int qr0 = g0 * 16 + col, qr1 = g1 * 16 + col;
#pragma unroll
    for (int ks = 0; ks < 2; ++ks) {
      qf[0][ks] = *(const s16x8*)(Qb + qr0 * 64 + (((ks * 4 + quad) ^ (col & 7)) * 8));
      qf[1][ks] = *(const s16x8*)(Qb + qr1 * 64 + (((ks * 4 + quad) ^ (col & 7)) * 8));
    }
  }

  f32x4 o[2][4] = {};
  float mst[2] = {-1.0e30f, -1.0e30f}, lst[2] = {0.0f, 0.0f};

  // softmax core: mask, tree row-max, defer-rescale (THR=8), exp2, cvt_pk pack,
  // immediate P write (lsum accumulation overlaps ds_write latency).
  auto sm = [&](f32x4 (&s)[4], bool diag, int qq, float& m, float& l,
                u16* Ps_, bool& deferred) -> float {
    float mx[4];
#pragma unroll
    for (int nt = 0; nt < 4; ++nt) {
      if (diag) {
#pragma unroll
        for (int r = 0; r < 4; ++r)
          if ((nt * 16 + quad * 4 + r) > qq) s[nt][r] = -1.0e30f;
      }
      mx[nt] = fmaxf(fmaxf(s[nt][0], s[nt][1]), fmaxf(s[nt][2], s[nt][3]));
    }
    float rmax = fmaxf(fmaxf(mx[0], mx[1]), fmaxf(mx[2], mx[3]));
    rmax = fmaxf(rmax, __shfl_xor(rmax, 16));
    rmax = fmaxf(rmax, __shfl_xor(rmax, 32));

    deferred = __all(rmax - m <= 8.0f);      // T13: P bounded by 2^8, keep old m
    float alpha = 1.0f;
    if (!deferred) {
      float mn = fmaxf(m, rmax);
      alpha = exp2f(m - mn);
      m = mn;
    }
    float lsum = 0.0f;
#pragma unroll
    for (int nt = 0; nt < 4; ++nt) {
      float p0 = exp2f(s[nt][0] - m), p1 = exp2f(s[nt][1] - m);
      float p2 = exp2f(s[nt][2] - m), p3 = exp2f(s[nt][3] - m);
      *(uint2*)(Ps_ + col * 64 + ((nt * 16 + quad * 4) ^ ((col & 7) << 3))) =
          make_uint2(cvtpk(p0, p1), cvtpk(p2, p3));
      lsum += (p0 + p1) + (p2 + p3);
    }
    l = l * alpha + lsum;
    return alpha;
  };

  for (int kt = 0; kt <= k1max; ++kt) {
    const bool both = (kt <= k0max);         // wave-uniform

    s16x8 kf[4][2], vf[4][2];
#pragma unroll
    for (int nt = 0; nt < 4; ++nt)
#pragma unroll
      for (int ks = 0; ks < 2; ++ks) {
        int key = kt * 64 + nt * 16 + col;
        kf[nt][ks] = *(const s16x8*)(KsB + key * 64 +
                                     (((ks * 4 + quad) ^ (col & 7)) * 8));
        int d = nt * 16 + col;
        vf[nt][ks] = *(const s16x8*)((const u16*)VTs + d * 256 +
                     ((kt * 64 + ks * 32 + quad * 8) ^ ((d & 15) << 3)));
      }

    // QK^T both groups back-to-back (independent MFMA chains fill the pipe)
    f32x4 sA[4] = {}, sB[4] = {};
    __builtin_amdgcn_s_setprio(1);
    if (both) {
#pragma unroll
      for (int ks = 0; ks < 2; ++ks)
#pragma unroll
        for (int nt = 0; nt < 4; ++nt)
          sA[nt] = __builtin_amdgcn_mfma_f32_16x16x32_bf16(kf[nt][ks], qf[0][ks],
                                                           sA[nt], 0, 0, 0);
    }
#pragma unroll
    for (int ks = 0; ks < 2; ++ks)
#pragma unroll
      for (int nt = 0; nt < 4; ++nt)
        sB[nt] = __builtin_amdgcn_mfma_f32_16x16x32_bf16(kf[nt][ks], qf[1][ks],
                                                         sB[nt], 0, 0, 0);
    __builtin_amdgcn_s_setprio(0);

    bool dfA = true, dfB;
    float aA = 1.0f, aB;
    if (both) aA = sm(sA, kt == k0max, qq0, mst[0], lst[0], PsA, dfA);
    aB = sm(sB, kt == k1max, qq1, mst[1], lst[1], PsB, dfB);

    // O-rescales (skipped when deferred) overlap the ds_write latency
    if (both && !dfA) {
#pragma unroll
      for (int dt = 0; dt < 4; ++dt)
#pragma unroll
        for (int r = 0; r < 4; ++r) o[0][dt][r] *= aA;
    }
    if (!dfB) {
#pragma unroll
      for (int dt = 0; dt < 4; ++dt)
#pragma unroll
        for (int r = 0; r < 4; ++r) o[1][dt][r] *= aB;
    }

    asm volatile("s_waitcnt lgkmcnt(0)" ::: "memory");  // P writes visible (own wave)

    s16x8 pfA[2], pfB[2];
    if (both) {
#pragma unroll
      for (int ks = 0; ks < 2; ++ks)
        pfA[ks] = *(const s16x8*)(PsA + col * 64 +
                                  ((ks * 32 + quad * 8) ^ ((col & 7) << 3)));
    }
#pragma unroll
    for (int ks = 0; ks < 2; ++ks)
      pfB[ks] = *(const s16x8*)(PsB + col * 64 +
                                ((ks * 32 + quad * 8) ^ ((col & 7) << 3)));

    __builtin_amdgcn_s_setprio(1);
    if (both) {
#pragma unroll
      for (int ks = 0; ks < 2; ++ks)
#pragma unroll
        for (int dt = 0; dt < 4; ++dt)
          o[0][dt] = __builtin_amdgcn_mfma_f32_16x16x32_bf16(vf[dt][ks], pfA[ks],
                                                             o[0][dt], 0, 0, 0);
    }
#pragma unroll
    for (int ks = 0; ks < 2; ++ks)
#pragma unroll
      for (int dt = 0; dt < 4; ++dt)
        o[1][dt] = __builtin_amdgcn_mfma_f32_16x16x32_bf16(vf[dt][ks], pfB[ks],
                                                           o[1][dt], 0, 0, 0);
    __builtin_amdgcn_s_setprio(0);
  }

  // epilogue: O^T row = d = dt*16+quad*4+r, col = q -> out[b,q,h*64+d]
#pragma unroll
  for (int gi = 0; gi < 2; ++gi) {
    int g = gi ? g1 : g0;
    float l = lst[gi];
    l += __shfl_xor(l, 16);
    l += __shfl_xor(l, 32);
    float inv = 1.0f / l;
    int q = g * 16 + col;
#pragma unroll
    for (int dt = 0; dt < 4; ++dt) {
      f32x4 res;
#pragma unroll
      for (int r = 0; r < 4; ++r) res[r] = o[gi][dt][r] * inv;
      *(f32x4*)(out + (size_t)(b * TT + q) * CC + h * DD + dt * 16 + quad * 4) = res;
    }
  }
}

extern "C" void kernel_launch(void* const* d_in, const int* in_sizes, int n_in,
                              void* d_out, int out_size, void* d_ws, size_t ws_size,
                              hipStream_t stream) {
  const float* x  = (const float*)d_in[0];
  const float* wq = (const float*)d_in[1];
  const float* wk = (const float*)d_in[2];
  const float* wv = (const float*)d_in[3];
  u16* ws  = (u16*)d_ws;
  float* out = (float*)d_out;

  prep_w<<<dim3(108), 256, 0, stream>>>(wq, wk, wv, ws);
  fused<<<dim3(BB * HH), 512, 0, stream>>>(x, ws, out);
}

// Round 8
// 168.783 us; speedup vs baseline: 1.4057x; 1.4057x over previous
//
#include <hip/hip_runtime.h>

// Causal MHA, B=128 T=256 C=384 H=6 d=64, fp32 in/out.
// prep_w: W->W^T bf16 via LDS tile transpose (Wq pre-scaled by 1/sqrt(C)*log2e). 108 blocks.
// fused: one block per (b,h), 512 thr = 8 waves, 128KB LDS, bounds(512,2)
//        (2 blocks/CU is register-infeasible: acc 96 + operands ~200 regs; R2's cap-128
//         spill cliff). X fp32->bf16 conversion FUSED into Phase-A staging (prep X-pass
//         deleted): reg-stage X with cvt_pk + swizzled ds_write (T14 issue-early /
//         write-late); W stays on global_load_lds.
//   Phase A: [256 tok x 192 n'], BK=64, R3-verified 2-barrier loop.
//   Epilogue: Q rows -> R1, K rows -> Ks, V^T -> VTs (LDS), XOR bank-swizzled.
//   Phase B: flash attention from LDS; waves own group pairs {w, 15-w} (5 visits);
//            dual-group interleave; defer-rescale THR=8 (T13); cvt_pk packs (T12);
//            setprio around MFMA clusters (T5).

typedef unsigned short u16;
typedef float f32x4 __attribute__((ext_vector_type(4)));
typedef short s16x8 __attribute__((ext_vector_type(8)));
typedef u16 u16x4 __attribute__((ext_vector_type(4)));

static constexpr int BB = 128;
static constexpr int TT = 256;
static constexpr int CC = 384;
static constexpr int HH = 6;
static constexpr int DD = 64;

// ws layout (u16): WT3 [1152][384] only
static constexpr float CSC = 0.07362242194579907f;  // (1/sqrt(384)) * log2(e)

__device__ __forceinline__ u16 f2bf(float f) {
  unsigned u = __float_as_uint(f);
  u += 0x7fffu + ((u >> 16) & 1u);   // RTN-even
  return (u16)(u >> 16);
}

// packed f32 pair -> bf16 pair (RTN-even), single VALU op
__device__ __forceinline__ unsigned cvtpk(float lo, float hi) {
  unsigned r;
  asm("v_cvt_pk_bf16_f32 %0, %1, %2" : "=v"(r) : "v"(lo), "v"(hi));
  return r;
}

__device__ __forceinline__ s16x8 pack4(unsigned a, unsigned b, unsigned c, unsigned d) {
  union { unsigned u[4]; s16x8 v; } t;
  t.u[0] = a; t.u[1] = b; t.u[2] = c; t.u[3] = d;
  return t.v;
}

// async global->LDS, 16 B/lane; LDS dest = wave-uniform base + lane*16 (m104)
__device__ __forceinline__ void g2l16(const u16* g, u16* l) {
  __builtin_amdgcn_global_load_lds(
      (const __attribute__((address_space(1))) u16*)g,
      (__attribute__((address_space(3))) u16*)l, 16, 0, 0);
}

// ---------- prep_w: W^T via LDS transpose (108 blocks: 3 z x 36 tiles of 64x64) ----------
__global__ void prep_w(const float* __restrict__ Wq, const float* __restrict__ Wk,
                       const float* __restrict__ Wv, u16* __restrict__ ws) {
  __shared__ u16 Lt[64][66];
  int j = blockIdx.x;
  int z = j / 36, t = j % 36, ti = t / 6, tj = t % 6;
  const float* W = (z == 0) ? Wq : (z == 1) ? Wk : Wv;
  const float sc = (z == 0) ? CSC : 1.0f;
  u16* WT = ws + (size_t)z * CC * CC;
  const int rl = threadIdx.x >> 4;
  const int cl = (threadIdx.x & 15) * 4;
#pragma unroll
  for (int it = 0; it < 4; ++it) {
    int r = it * 16 + rl;
    f32x4 v = *(const f32x4*)(W + (size_t)(ti * 64 + r) * CC + tj * 64 + cl);
#pragma unroll
    for (int q = 0; q < 4; ++q) Lt[r][cl + q] = f2bf(v[q] * sc);
  }
  __syncthreads();
#pragma unroll
  for (int it = 0; it < 4; ++it) {
    int n = it * 16 + rl;
    u16x4 o;
#pragma unroll
    for (int q = 0; q < 4; ++q) o[q] = Lt[cl + q][n];
    *(u16x4*)(WT + (size_t)(tj * 64 + n) * CC + ti * 64 + cl) = o;
  }
}

// ---------- fused QKV projection + flash attention ----------
__global__ __launch_bounds__(512, 2) void fused(const float* __restrict__ X,
                                                const u16* __restrict__ ws,
                                                float* __restrict__ out) {
  // XCD clustering: 6 heads of same b share ids congruent mod 8 -> same XCD L2
  const int bid = blockIdx.x;
  const int xc = bid & 7;
  const int g5 = bid >> 3;           // 0..95
  const int b = xc * 16 + g5 / 6;
  const int h = g5 % 6;

  __shared__ u16 R1[256][64];        // A: X stage (swz); B: Q rows (swz)
  __shared__ u16 R2[16384];          // A: W stage (12288 used); B: Ps (8 x 2048)
  __shared__ u16 Ks[256][64];        // K rows, XOR-swizzled (epilogue)
  __shared__ u16 VTs[64][256];       // V^T, XOR-swizzled (epilogue)

  const int tid = threadIdx.x;
  const int lane = tid & 63;
  const int w = tid >> 6;            // 0..7
  const int quad = lane >> 4;
  const int col = lane & 15;

  const float* Xf = X + (size_t)b * TT * CC;   // [256][384] fp32
  const u16* Wg = ws;                          // [1152][384] bf16
  u16* Wst = R2;                               // [192][64] staging view

  const int rl8 = lane >> 3;         // row within 8-row staging chunk
  const int cb  = lane & 7;          // this lane's global 8-col block (X path)
  const int gb  = cb ^ rl8;          // pre-swizzled source block (W g2l16 path)

  const int wm = (w >> 1) * 64;      // token quadrant
  const int wn = (w & 1) * 96;       // n' half (Q:0-63 K:64-127 V:128-191)

  // ---------------- Phase A: R3 2-barrier loop; X reg-staged fp32->bf16 ----------------
  f32x4 acc[4][6] = {};

  // prologue: stage tile 0
#pragma unroll
  for (int i = 0; i < 4; ++i) {
    int r = w * 32 + i * 8 + rl8;
    const float* src = Xf + (size_t)r * CC + cb * 8;
    f32x4 x0 = *(const f32x4*)(src);
    f32x4 x1 = *(const f32x4*)(src + 4);
    *(s16x8*)(&R1[r][((cb ^ (r & 7)) * 8)]) =
        pack4(cvtpk(x0[0], x0[1]), cvtpk(x0[2], x0[3]),
              cvtpk(x1[0], x1[1]), cvtpk(x1[2], x1[3]));
  }
#pragma unroll
  for (int i = 0; i < 3; ++i) {
    int r0 = w * 24 + i * 8;
    int rr = r0 + rl8;
    int z = rr >> 6, nn = rr & 63;
    g2l16(Wg + (size_t)(z * CC + h * DD + nn) * CC + gb * 8, Wst + r0 * 64);
  }
  __syncthreads();                   // drains vmcnt + lgkm, then barrier

  for (int kt = 0; kt < 6; ++kt) {
    // T14 issue-early: global fp32 loads for X(kt+1) fly under everything below
    f32x4 xr[4][2];
    if (kt < 5) {
#pragma unroll
      for (int i = 0; i < 4; ++i) {
        int r = w * 32 + i * 8 + rl8;
        const float* src = Xf + (size_t)r * CC + (kt + 1) * 64 + cb * 8;
        xr[i][0] = *(const f32x4*)(src);
        xr[i][1] = *(const f32x4*)(src + 4);
      }
    }

    s16x8 af[4][2], bf[6][2];
#pragma unroll
    for (int mt = 0; mt < 4; ++mt)
#pragma unroll
      for (int ks = 0; ks < 2; ++ks)
        af[mt][ks] = *(const s16x8*)(&R1[wm + mt * 16 + col]
                                        [(((ks * 4 + quad) ^ (col & 7)) * 8)]);
#pragma unroll
    for (int nt = 0; nt < 6; ++nt)
#pragma unroll
      for (int ks = 0; ks < 2; ++ks)
        bf[nt][ks] = *(const s16x8*)(Wst + (wn + nt * 16 + col) * 64 +
                                     (((ks * 4 + quad) ^ (col & 7)) * 8));

    __syncthreads();                 // (a) all waves done reading this tile

    if (kt < 5) {
#pragma unroll
      for (int i = 0; i < 3; ++i) {  // W async into Wst
        int r0 = w * 24 + i * 8;
        int rr = r0 + rl8;
        int z = rr >> 6, nn = rr & 63;
        g2l16(Wg + (size_t)(z * CC + h * DD + nn) * CC + (kt + 1) * 64 + gb * 8,
              Wst + r0 * 64);
      }
      // X write-late: cvt + swizzled ds_write (overlaps MFMAs below)
#pragma unroll
      for (int i = 0; i < 4; ++i) {
        int r = w * 32 + i * 8 + rl8;
        *(s16x8*)(&R1[r][((cb ^ (r & 7)) * 8)]) =
            pack4(cvtpk(xr[i][0][0], xr[i][0][1]), cvtpk(xr[i][0][2], xr[i][0][3]),
                  cvtpk(xr[i][1][0], xr[i][1][1]), cvtpk(xr[i][1][2], xr[i][1][3]));
      }
    }

    __builtin_amdgcn_s_setprio(1);
#pragma unroll
    for (int ks = 0; ks < 2; ++ks)
#pragma unroll
      for (int mt = 0; mt < 4; ++mt)
#pragma unroll
        for (int nt = 0; nt < 6; ++nt)
          acc[mt][nt] = __builtin_amdgcn_mfma_f32_16x16x32_bf16(
              af[mt][ks], bf[nt][ks], acc[mt][nt], 0, 0, 0);
    __builtin_amdgcn_s_setprio(0);

    if (kt < 5) __syncthreads();     // (b) drains W vmcnt + X ds_writes; tile visible
  }
  // no barrier: (a) at kt=5 ordered all reads before epilogue overlay writes

  // ------ Epilogue: acc -> Q(R1)/K(Ks) rows, V^T(VTs); XOR bank-swizzle ------
  u16* Qb  = &R1[0][0];
  u16* KsB = &Ks[0][0];
#pragma unroll
  for (int mt = 0; mt < 4; ++mt) {
    int tokb = wm + mt * 16 + quad * 4;
#pragma unroll
    for (int nt = 0; nt < 6; ++nt) {
      int gn = wn + nt * 16 + col;           // class uniform per (w,nt)
      unsigned u01 = cvtpk(acc[mt][nt][0], acc[mt][nt][1]);
      unsigned u23 = cvtpk(acc[mt][nt][2], acc[mt][nt][3]);
      if (gn < 128) {
        u16* dst = (gn < 64) ? Qb : KsB;
        int d = gn & 63;
        dst[(tokb + 0) * 64 + (d ^ (((tokb + 0) & 7) << 3))] = (u16)u01;
        dst[(tokb + 1) * 64 + (d ^ (((tokb + 1) & 7) << 3))] = (u16)(u01 >> 16);
        dst[(tokb + 2) * 64 + (d ^ (((tokb + 2) & 7) << 3))] = (u16)u23;
        dst[(tokb + 3) * 64 + (d ^ (((tokb + 3) & 7) << 3))] = (u16)(u23 >> 16);
      } else {
        int d = gn - 128;
        *(uint2*)((u16*)VTs + d * 256 + (tokb ^ ((d & 15) << 3))) =
            make_uint2(u01, u23);
      }
    }
  }
  __syncthreads();

  // ---------------- Phase B: flash attention from LDS, barrier-free ----------------
  const int g0 = w, g1 = 15 - w;             // this wave's two q-groups
  const int k0max = g0 >> 2, k1max = g1 >> 2;
  const int qq0 = (g0 & 3) * 16 + col;
  const int qq1 = (g1 & 3) * 16 + col;
  u16* PsA = R2 + w * 2048;                  // per-wave [16][64] swizzled
  u16* PsB = PsA + 1024;

  s16x8 qf[2][2];
  {
    int qr0 = g0 * 16 + col, qr1 = g1 * 16 + col;
#pragma unroll
    for (int ks = 0; ks < 2; ++ks) {
      qf[0][ks] = *(const s16x8*)(Qb + qr0 * 64 + (((ks * 4 + quad) ^ (col & 7)) * 8));
      qf[1][ks] = *(const s16x8*)(Qb + qr1 * 64 + (((ks * 4 + quad) ^ (col & 7)) * 8));
    }
  }

  f32x4 o[2][4] = {};
  float mst[2] = {-1.0e30f, -1.0e30f}, lst[2] = {0.0f, 0.0f};

  // softmax core: mask, tree row-max, defer-rescale (THR=8), exp2, cvt_pk pack,
  // immediate P write (lsum accumulation overlaps ds_write latency).
  auto sm = [&](f32x4 (&s)[4], bool diag, int qq, float& m, float& l,
                u16* Ps_, bool& deferred) -> float {
    float mx[4];
#pragma unroll
    for (int nt = 0; nt < 4; ++nt) {
      if (diag) {
#pragma unroll
        for (int r = 0; r < 4; ++r)
          if ((nt * 16 + quad * 4 + r) > qq) s[nt][r] = -1.0e30f;
      }
      mx[nt] = fmaxf(fmaxf(s[nt][0], s[nt][1]), fmaxf(s[nt][2], s[nt][3]));
    }
    float rmax = fmaxf(fmaxf(mx[0], mx[1]), fmaxf(mx[2], mx[3]));
    rmax = fmaxf(rmax, __shfl_xor(rmax, 16));
    rmax = fmaxf(rmax, __shfl_xor(rmax, 32));

    deferred = __all(rmax - m <= 8.0f);      // T13: P bounded by 2^8, keep old m
    float alpha = 1.0f;
    if (!deferred) {
      float mn = fmaxf(m, rmax);
      alpha = exp2f(m - mn);
      m = mn;
    }
    float lsum = 0.0f;
#pragma unroll
    for (int nt = 0; nt < 4; ++nt) {
      float p0 = exp2f(s[nt][0] - m), p1 = exp2f(s[nt][1] - m);
      float p2 = exp2f(s[nt][2] - m), p3 = exp2f(s[nt][3] - m);
      *(uint2*)(Ps_ + col * 64 + ((nt * 16 + quad * 4) ^ ((col & 7) << 3))) =
          make_uint2(cvtpk(p0, p1), cvtpk(p2, p3));
      lsum += (p0 + p1) + (p2 + p3);
    }
    l = l * alpha + lsum;
    return alpha;
  };

  for (int kt = 0; kt <= k1max; ++kt) {
    const bool both = (kt <= k0max);         // wave-uniform

    s16x8 kf[4][2], vf[4][2];
#pragma unroll
    for (int nt = 0; nt < 4; ++nt)
#pragma unroll
      for (int ks = 0; ks < 2; ++ks) {
        int key = kt * 64 + nt * 16 + col;
        kf[nt][ks] = *(const s16x8*)(KsB + key * 64 +
                                     (((ks * 4 + quad) ^ (col & 7)) * 8));
        int d = nt * 16 + col;
        vf[nt][ks] = *(const s16x8*)((const u16*)VTs + d * 256 +
                     ((kt * 64 + ks * 32 + quad * 8) ^ ((d & 15) << 3)));
      }

    // QK^T both groups back-to-back (independent MFMA chains fill the pipe)
    f32x4 sA[4] = {}, sB[4] = {};
    __builtin_amdgcn_s_setprio(1);
    if (both) {
#pragma unroll
      for (int ks = 0; ks < 2; ++ks)
#pragma unroll
        for (int nt = 0; nt < 4; ++nt)
          sA[nt] = __builtin_amdgcn_mfma_f32_16x16x32_bf16(kf[nt][ks], qf[0][ks],
                                                           sA[nt], 0, 0, 0);
    }
#pragma unroll
    for (int ks = 0; ks < 2; ++ks)
#pragma unroll
      for (int nt = 0; nt < 4; ++nt)
        sB[nt] = __builtin_amdgcn_mfma_f32_16x16x32_bf16(kf[nt][ks], qf[1][ks],
                                                         sB[nt], 0, 0, 0);
    __builtin_amdgcn_s_setprio(0);

    bool dfA = true, dfB;
    float aA = 1.0f, aB;
    if (both) aA = sm(sA, kt == k0max, qq0, mst[0], lst[0], PsA, dfA);
    aB = sm(sB, kt == k1max, qq1, mst[1], lst[1], PsB, dfB);

    // O-rescales (skipped when deferred) overlap the ds_write latency
    if (both && !dfA) {
#pragma unroll
      for (int dt = 0; dt < 4; ++dt)
#pragma unroll
        for (int r = 0; r < 4; ++r) o[0][dt][r] *= aA;
    }
    if (!dfB) {
#pragma unroll
      for (int dt = 0; dt < 4; ++dt)
#pragma unroll
        for (int r = 0; r < 4; ++r) o[1][dt][r] *= aB;
    }

    asm volatile("s_waitcnt lgkmcnt(0)" ::: "memory");  // P writes visible (own wave)

    s16x8 pfA[2], pfB[2];
    if (both) {
#pragma unroll
      for (int ks = 0; ks < 2; ++ks)
        pfA[ks] = *(const s16x8*)(PsA + col * 64 +
                                  ((ks * 32 + quad * 8) ^ ((col & 7) << 3)));
    }
#pragma unroll
    for (int ks = 0; ks < 2; ++ks)
      pfB[ks] = *(const s16x8*)(PsB + col * 64 +
                                ((ks * 32 + quad * 8) ^ ((col & 7) << 3)));

    __builtin_amdgcn_s_setprio(1);
    if (both) {
#pragma unroll
      for (int ks = 0; ks < 2; ++ks)
#pragma unroll
        for (int dt = 0; dt < 4; ++dt)
          o[0][dt] = __builtin_amdgcn_mfma_f32_16x16x32_bf16(vf[dt][ks], pfA[ks],
                                                             o[0][dt], 0, 0, 0);
    }
#pragma unroll
    for (int ks = 0; ks < 2; ++ks)
#pragma unroll
      for (int dt = 0; dt < 4; ++dt)
        o[1][dt] = __builtin_amdgcn_mfma_f32_16x16x32_bf16(vf[dt][ks], pfB[ks],
                                                           o[1][dt], 0, 0, 0);
    __builtin_amdgcn_s_setprio(0);
  }

  // epilogue: O^T row = d = dt*16+quad*4+r, col = q -> out[b,q,h*64+d]
#pragma unroll
  for (int gi = 0; gi < 2; ++gi) {
    int g = gi ? g1 : g0;
    float l = lst[gi];
    l += __shfl_xor(l, 16);
    l += __shfl_xor(l, 32);
    float inv = 1.0f / l;
    int q = g * 16 + col;
#pragma unroll
    for (int dt = 0; dt < 4; ++dt) {
      f32x4 res;
#pragma unroll
      for (int r = 0; r < 4; ++r) res[r] = o[gi][dt][r] * inv;
      *(f32x4*)(out + (size_t)(b * TT + q) * CC + h * DD + dt * 16 + quad * 4) = res;
    }
  }
}

extern "C" void kernel_launch(void* const* d_in, const int* in_sizes, int n_in,
                              void* d_out, int out_size, void* d_ws, size_t ws_size,
                              hipStream_t stream) {
  const float* x  = (const float*)d_in[0];
  const float* wq = (const float*)d_in[1];
  const float* wk = (const float*)d_in[2];
  const float* wv = (const float*)d_in[3];
  u16* ws  = (u16*)d_ws;
  float* out = (float*)d_out;

  prep_w<<<dim3(108), 256, 0, stream>>>(wq, wk, wv, ws);
  fused<<<dim3(BB * HH), 512, 0, stream>>>(x, ws, out);
}

// Round 9
// 159.549 us; speedup vs baseline: 1.4870x; 1.0579x over previous
//
#include <hip/hip_runtime.h>

// Causal MHA, B=128 T=256 C=384 H=6 d=64, fp32 in/out.
// prep_w: W->W^T bf16 via LDS tile transpose (Wq pre-scaled by 1/sqrt(C)*log2e). 108 blocks.
// fused: one block per (b,h), 512 thr = 8 waves, 128KB LDS, bounds(512,2).
//        X fp32->bf16 fused into Phase-A staging (no X prep pass):
//        loads issued at iter top, kept IN FLIGHT across barrier (a) (raw s_barrier +
//        lgkmcnt-only wait - no vmcnt drain), consumed AFTER the MFMA cluster (write-late).
//        R8's regression isolated to: __syncthreads vmcnt(0) drain at (a) + early consume.
//   Phase A: [256 tok x 192 n'], BK=64, 2-barrier loop; W on global_load_lds.
//   Epilogue: Q rows -> R1, K rows -> Ks, V^T -> VTs (LDS), XOR bank-swizzled.
//   Phase B: flash attention from LDS; waves own group pairs {w, 15-w} (5 visits);
//            dual-group interleave; defer-rescale THR=8 (T13); cvt_pk packs (T12);
//            setprio around MFMA clusters (T5).

typedef unsigned short u16;
typedef float f32x4 __attribute__((ext_vector_type(4)));
typedef short s16x8 __attribute__((ext_vector_type(8)));
typedef u16 u16x4 __attribute__((ext_vector_type(4)));

static constexpr int BB = 128;
static constexpr int TT = 256;
static constexpr int CC = 384;
static constexpr int HH = 6;
static constexpr int DD = 64;

// ws layout (u16): WT3 [1152][384] only
static constexpr float CSC = 0.07362242194579907f;  // (1/sqrt(384)) * log2(e)

__device__ __forceinline__ u16 f2bf(float f) {
  unsigned u = __float_as_uint(f);
  u += 0x7fffu + ((u >> 16) & 1u);   // RTN-even
  return (u16)(u >> 16);
}

// packed f32 pair -> bf16 pair (RTN-even), single VALU op
__device__ __forceinline__ unsigned cvtpk(float lo, float hi) {
  unsigned r;
  asm("v_cvt_pk_bf16_f32 %0, %1, %2" : "=v"(r) : "v"(lo), "v"(hi));
  return r;
}

__device__ __forceinline__ s16x8 pack4(unsigned a, unsigned b, unsigned c, unsigned d) {
  union { unsigned u[4]; s16x8 v; } t;
  t.u[0] = a; t.u[1] = b; t.u[2] = c; t.u[3] = d;
  return t.v;
}

// async global->LDS, 16 B/lane; LDS dest = wave-uniform base + lane*16 (m104)
__device__ __forceinline__ void g2l16(const u16* g, u16* l) {
  __builtin_amdgcn_global_load_lds(
      (const __attribute__((address_space(1))) u16*)g,
      (__attribute__((address_space(3))) u16*)l, 16, 0, 0);
}

// ---------- prep_w: W^T via LDS transpose (108 blocks: 3 z x 36 tiles of 64x64) ----------
__global__ void prep_w(const float* __restrict__ Wq, const float* __restrict__ Wk,
                       const float* __restrict__ Wv, u16* __restrict__ ws) {
  __shared__ u16 Lt[64][66];
  int j = blockIdx.x;
  int z = j / 36, t = j % 36, ti = t / 6, tj = t % 6;
  const float* W = (z == 0) ? Wq : (z == 1) ? Wk : Wv;
  const float sc = (z == 0) ? CSC : 1.0f;
  u16* WT = ws + (size_t)z * CC * CC;
  const int rl = threadIdx.x >> 4;
  const int cl = (threadIdx.x & 15) * 4;
#pragma unroll
  for (int it = 0; it < 4; ++it) {
    int r = it * 16 + rl;
    f32x4 v = *(const f32x4*)(W + (size_t)(ti * 64 + r) * CC + tj * 64 + cl);
#pragma unroll
    for (int q = 0; q < 4; ++q) Lt[r][cl + q] = f2bf(v[q] * sc);
  }
  __syncthreads();
#pragma unroll
  for (int it = 0; it < 4; ++it) {
    int n = it * 16 + rl;
    u16x4 o;
#pragma unroll
    for (int q = 0; q < 4; ++q) o[q] = Lt[cl + q][n];
    *(u16x4*)(WT + (size_t)(tj * 64 + n) * CC + ti * 64 + cl) = o;
  }
}

// ---------- fused QKV projection + flash attention ----------
__global__ __launch_bounds__(512, 2) void fused(const float* __restrict__ X,
                                                const u16* __restrict__ ws,
                                                float* __restrict__ out) {
  // XCD clustering: 6 heads of same b share ids congruent mod 8 -> same XCD L2
  const int bid = blockIdx.x;
  const int xc = bid & 7;
  const int g5 = bid >> 3;           // 0..95
  const int b = xc * 16 + g5 / 6;
  const int h = g5 % 6;

  __shared__ u16 R1[256][64];        // A: X stage (swz); B: Q rows (swz)
  __shared__ u16 R2[16384];          // A: W stage (12288 used); B: Ps (8 x 2048)
  __shared__ u16 Ks[256][64];        // K rows, XOR-swizzled (epilogue)
  __shared__ u16 VTs[64][256];       // V^T, XOR-swizzled (epilogue)

  const int tid = threadIdx.x;
  const int lane = tid & 63;
  const int w = tid >> 6;            // 0..7
  const int quad = lane >> 4;
  const int col = lane & 15;

  const float* Xf = X + (size_t)b * TT * CC;   // [256][384] fp32
  const u16* Wg = ws;                          // [1152][384] bf16
  u16* Wst = R2;                               // [192][64] staging view

  const int rl8 = lane >> 3;         // row within 8-row staging chunk
  const int cb  = lane & 7;          // this lane's global 8-col block (X path)
  const int gb  = cb ^ rl8;          // pre-swizzled source block (W g2l16 path)

  const int wm = (w >> 1) * 64;      // token quadrant
  const int wn = (w & 1) * 96;       // n' half (Q:0-63 K:64-127 V:128-191)

  // ---------------- Phase A: 2-barrier loop; X reg-staged fp32->bf16 ----------------
  f32x4 acc[4][6] = {};

  // prologue: stage tile 0 (exposed latency once)
#pragma unroll
  for (int i = 0; i < 4; ++i) {
    int r = w * 32 + i * 8 + rl8;
    const float* src = Xf + (size_t)r * CC + cb * 8;
    f32x4 x0 = *(const f32x4*)(src);
    f32x4 x1 = *(const f32x4*)(src + 4);
    *(s16x8*)(&R1[r][((cb ^ (r & 7)) * 8)]) =
        pack4(cvtpk(x0[0], x0[1]), cvtpk(x0[2], x0[3]),
              cvtpk(x1[0], x1[1]), cvtpk(x1[2], x1[3]));
  }
#pragma unroll
  for (int i = 0; i < 3; ++i) {
    int r0 = w * 24 + i * 8;
    int rr = r0 + rl8;
    int z = rr >> 6, nn = rr & 63;
    g2l16(Wg + (size_t)(z * CC + h * DD + nn) * CC + gb * 8, Wst + r0 * 64);
  }
  __syncthreads();                   // full drain + barrier (prologue only)

  for (int kt = 0; kt < 6; ++kt) {
    // issue-early: global fp32 loads for X(kt+1); stay IN FLIGHT across barrier (a)
    f32x4 xr[4][2];
    if (kt < 5) {
#pragma unroll
      for (int i = 0; i < 4; ++i) {
        int r = w * 32 + i * 8 + rl8;
        const float* src = Xf + (size_t)r * CC + (kt + 1) * 64 + cb * 8;
        xr[i][0] = *(const f32x4*)(src);
        xr[i][1] = *(const f32x4*)(src + 4);
      }
    }

    s16x8 af[4][2], bf[6][2];
#pragma unroll
    for (int mt = 0; mt < 4; ++mt)
#pragma unroll
      for (int ks = 0; ks < 2; ++ks)
        af[mt][ks] = *(const s16x8*)(&R1[wm + mt * 16 + col]
                                        [(((ks * 4 + quad) ^ (col & 7)) * 8)]);
#pragma unroll
    for (int nt = 0; nt < 6; ++nt)
#pragma unroll
      for (int ks = 0; ks < 2; ++ks)
        bf[nt][ks] = *(const s16x8*)(Wst + (wn + nt * 16 + col) * 64 +
                                     (((ks * 4 + quad) ^ (col & 7)) * 8));

    // barrier (a): WAR on LDS only -> lgkm drain, NO vmcnt drain (xr stays in flight)
    asm volatile("s_waitcnt lgkmcnt(0)" ::: "memory");
    __builtin_amdgcn_s_barrier();

    if (kt < 5) {
#pragma unroll
      for (int i = 0; i < 3; ++i) {  // W async into Wst
        int r0 = w * 24 + i * 8;
        int rr = r0 + rl8;
        int z = rr >> 6, nn = rr & 63;
        g2l16(Wg + (size_t)(z * CC + h * DD + nn) * CC + (kt + 1) * 64 + gb * 8,
              Wst + r0 * 64);
      }
    }

    __builtin_amdgcn_s_setprio(1);
#pragma unroll
    for (int ks = 0; ks < 2; ++ks)
#pragma unroll
      for (int mt = 0; mt < 4; ++mt)
#pragma unroll
        for (int nt = 0; nt < 6; ++nt)
          acc[mt][nt] = __builtin_amdgcn_mfma_f32_16x16x32_bf16(
              af[mt][ks], bf[nt][ks], acc[mt][nt], 0, 0, 0);
    __builtin_amdgcn_s_setprio(0);

    // write-late: xr consumed AFTER the MFMA cluster (~400-600 cyc of cover)
    if (kt < 5) {
#pragma unroll
      for (int i = 0; i < 4; ++i) {
        int r = w * 32 + i * 8 + rl8;
        *(s16x8*)(&R1[r][((cb ^ (r & 7)) * 8)]) =
            pack4(cvtpk(xr[i][0][0], xr[i][0][1]), cvtpk(xr[i][0][2], xr[i][0][3]),
                  cvtpk(xr[i][1][0], xr[i][1][1]), cvtpk(xr[i][1][2], xr[i][1][3]));
      }
      __syncthreads();               // (b) drains W vmcnt + X ds_writes; tile visible
    }
  }
  // no barrier: (a) at kt=5 ordered all reads before epilogue overlay writes

  // ------ Epilogue: acc -> Q(R1)/K(Ks) rows, V^T(VTs); XOR bank-swizzle ------
  u16* Qb  = &R1[0][0];
  u16* KsB = &Ks[0][0];
#pragma unroll
  for (int mt = 0; mt < 4; ++mt) {
    int tokb = wm + mt * 16 + quad * 4;
#pragma unroll
    for (int nt = 0; nt < 6; ++nt) {
      int gn = wn + nt * 16 + col;           // class uniform per (w,nt)
      unsigned u01 = cvtpk(acc[mt][nt][0], acc[mt][nt][1]);
      unsigned u23 = cvtpk(acc[mt][nt][2], acc[mt][nt][3]);
      if (gn < 128) {
        u16* dst = (gn < 64) ? Qb : KsB;
        int d = gn & 63;
        dst[(tokb + 0) * 64 + (d ^ (((tokb + 0) & 7) << 3))] = (u16)u01;
        dst[(tokb + 1) * 64 + (d ^ (((tokb + 1) & 7) << 3))] = (u16)(u01 >> 16);
        dst[(tokb + 2) * 64 + (d ^ (((tokb + 2) & 7) << 3))] = (u16)u23;
        dst[(tokb + 3) * 64 + (d ^ (((tokb + 3) & 7) << 3))] = (u16)(u23 >> 16);
      } else {
        int d = gn - 128;
        *(uint2*)((u16*)VTs + d * 256 + (tokb ^ ((d & 15) << 3))) =
            make_uint2(u01, u23);
      }
    }
  }
  __syncthreads();

  // ---------------- Phase B: flash attention from LDS, barrier-free ----------------
  const int g0 = w, g1 = 15 - w;             // this wave's two q-groups
  const int k0max = g0 >> 2, k1max = g1 >> 2;
  const int qq0 = (g0 & 3) * 16 + col;
  const int qq1 = (g1 & 3) * 16 + col;
  u16* PsA = R2 + w * 2048;                  // per-wave [16][64] swizzled
  u16* PsB = PsA + 1024;

  s16x8 qf[2][2];
  {
    int qr0 = g0 * 16 + col, qr1 = g1 * 16 + col;
#pragma unroll
    for (int ks = 0; ks < 2; ++ks) {
      qf[0][ks] = *(const s16x8*)(Qb + qr0 * 64 + (((ks * 4 + quad) ^ (col & 7)) * 8));
      qf[1][ks] = *(const s16x8*)(Qb + qr1 * 64 + (((ks * 4 + quad) ^ (col & 7)) * 8));
    }
  }

  f32x4 o[2][4] = {};
  float mst[2] = {-1.0e30f, -1.0e30f}, lst[2] = {0.0f, 0.0f};

  // softmax core: mask, tree row-max, defer-rescale (THR=8), exp2, cvt_pk pack,
  // immediate P write (lsum accumulation overlaps ds_write latency).
  auto sm = [&](f32x4 (&s)[4], bool diag, int qq, float& m, float& l,
                u16* Ps_, bool& deferred) -> float {
    float mx[4];
#pragma unroll
    for (int nt = 0; nt < 4; ++nt) {
      if (diag) {
#pragma unroll
        for (int r = 0; r < 4; ++r)
          if ((nt * 16 + quad * 4 + r) > qq) s[nt][r] = -1.0e30f;
      }
      mx[nt] = fmaxf(fmaxf(s[nt][0], s[nt][1]), fmaxf(s[nt][2], s[nt][3]));
    }
    float rmax = fmaxf(fmaxf(mx[0], mx[1]), fmaxf(mx[2], mx[3]));
    rmax = fmaxf(rmax, __shfl_xor(rmax, 16));
    rmax = fmaxf(rmax, __shfl_xor(rmax, 32));

    deferred = __all(rmax - m <= 8.0f);      // T13: P bounded by 2^8, keep old m
    float alpha = 1.0f;
    if (!deferred) {
      float mn = fmaxf(m, rmax);
      alpha = exp2f(m - mn);
      m = mn;
    }
    float lsum = 0.0f;
#pragma unroll
    for (int nt = 0; nt < 4; ++nt) {
      float p0 = exp2f(s[nt][0] - m), p1 = exp2f(s[nt][1] - m);
      float p2 = exp2f(s[nt][2] - m), p3 = exp2f(s[nt][3] - m);
      *(uint2*)(Ps_ + col * 64 + ((nt * 16 + quad * 4) ^ ((col & 7) << 3))) =
          make_uint2(cvtpk(p0, p1), cvtpk(p2, p3));
      lsum += (p0 + p1) + (p2 + p3);
    }
    l = l * alpha + lsum;
    return alpha;
  };

  for (int kt = 0; kt <= k1max; ++kt) {
    const bool both = (kt <= k0max);         // wave-uniform

    s16x8 kf[4][2], vf[4][2];
#pragma unroll
    for (int nt = 0; nt < 4; ++nt)
#pragma unroll
      for (int ks = 0; ks < 2; ++ks) {
        int key = kt * 64 + nt * 16 + col;
        kf[nt][ks] = *(const s16x8*)(KsB + key * 64 +
                                     (((ks * 4 + quad) ^ (col & 7)) * 8));
        int d = nt * 16 + col;
        vf[nt][ks] = *(const s16x8*)((const u16*)VTs + d * 256 +
                     ((kt * 64 + ks * 32 + quad * 8) ^ ((d & 15) << 3)));
      }

    // QK^T both groups back-to-back (independent MFMA chains fill the pipe)
    f32x4 sA[4] = {}, sB[4] = {};
    __builtin_amdgcn_s_setprio(1);
    if (both) {
#pragma unroll
      for (int ks = 0; ks < 2; ++ks)
#pragma unroll
        for (int nt = 0; nt < 4; ++nt)
          sA[nt] = __builtin_amdgcn_mfma_f32_16x16x32_bf16(kf[nt][ks], qf[0][ks],
                                                           sA[nt], 0, 0, 0);
    }
#pragma unroll
    for (int ks = 0; ks < 2; ++ks)
#pragma unroll
      for (int nt = 0; nt < 4; ++nt)
        sB[nt] = __builtin_amdgcn_mfma_f32_16x16x32_bf16(kf[nt][ks], qf[1][ks],
                                                         sB[nt], 0, 0, 0);
    __builtin_amdgcn_s_setprio(0);

    bool dfA = true, dfB;
    float aA = 1.0f, aB;
    if (both) aA = sm(sA, kt == k0max, qq0, mst[0], lst[0], PsA, dfA);
    aB = sm(sB, kt == k1max, qq1, mst[1], lst[1], PsB, dfB);

    // O-rescales (skipped when deferred) overlap the ds_write latency
    if (both && !dfA) {
#pragma unroll
      for (int dt = 0; dt < 4; ++dt)
#pragma unroll
        for (int r = 0; r < 4; ++r) o[0][dt][r] *= aA;
    }
    if (!dfB) {
#pragma unroll
      for (int dt = 0; dt < 4; ++dt)
#pragma unroll
        for (int r = 0; r < 4; ++r) o[1][dt][r] *= aB;
    }

    asm volatile("s_waitcnt lgkmcnt(0)" ::: "memory");  // P writes visible (own wave)

    s16x8 pfA[2], pfB[2];
    if (both) {
#pragma unroll
      for (int ks = 0; ks < 2; ++ks)
        pfA[ks] = *(const s16x8*)(PsA + col * 64 +
                                  ((ks * 32 + quad * 8) ^ ((col & 7) << 3)));
    }
#pragma unroll
    for (int ks = 0; ks < 2; ++ks)
      pfB[ks] = *(const s16x8*)(PsB + col * 64 +
                                ((ks * 32 + quad * 8) ^ ((col & 7) << 3)));

    __builtin_amdgcn_s_setprio(1);
    if (both) {
#pragma unroll
      for (int ks = 0; ks < 2; ++ks)
#pragma unroll
        for (int dt = 0; dt < 4; ++dt)
          o[0][dt] = __builtin_amdgcn_mfma_f32_16x16x32_bf16(vf[dt][ks], pfA[ks],
                                                             o[0][dt], 0, 0, 0);
    }
#pragma unroll
    for (int ks = 0; ks < 2; ++ks)
#pragma unroll
      for (int dt = 0; dt < 4; ++dt)
        o[1][dt] = __builtin_amdgcn_mfma_f32_16x16x32_bf16(vf[dt][ks], pfB[ks],
                                                           o[1][dt], 0, 0, 0);
    __builtin_amdgcn_s_setprio(0);
  }

  // epilogue: O^T row = d = dt*16+quad*4+r, col = q -> out[b,q,h*64+d]
#pragma unroll
  for (int gi = 0; gi < 2; ++gi) {
    int g = gi ? g1 : g0;
    float l = lst[gi];
    l += __shfl_xor(l, 16);
    l += __shfl_xor(l, 32);
    float inv = 1.0f / l;
    int q = g * 16 + col;
#pragma unroll
    for (int dt = 0; dt < 4; ++dt) {
      f32x4 res;
#pragma unroll
      for (int r = 0; r < 4; ++r) res[r] = o[gi][dt][r] * inv;
      *(f32x4*)(out + (size_t)(b * TT + q) * CC + h * DD + dt * 16 + quad * 4) = res;
    }
  }
}

extern "C" void kernel_launch(void* const* d_in, const int* in_sizes, int n_in,
                              void* d_out, int out_size, void* d_ws, size_t ws_size,
                              hipStream_t stream) {
  const float* x  = (const float*)d_in[0];
  const float* wq = (const float*)d_in[1];
  const float* wk = (const float*)d_in[2];
  const float* wv = (const float*)d_in[3];
  u16* ws  = (u16*)d_ws;
  float* out = (float*)d_out;

  prep_w<<<dim3(108), 256, 0, stream>>>(wq, wk, wv, ws);
  fused<<<dim3(BB * HH), 512, 0, stream>>>(x, ws, out);
}

// Round 10
// 153.243 us; speedup vs baseline: 1.5482x; 1.0411x over previous
//
#include <hip/hip_runtime.h>

// Causal MHA, B=128 T=256 C=384 H=6 d=64, fp32 in/out.
// prep: X->bf16; W->W^T bf16 via LDS tile transpose (Wq pre-scaled by 1/sqrt(C)*log2e).
// fused: one block per (b,h), 512 thr = 8 waves, 144KB LDS.
//   Phase A: QKV projection [256 tok x 192 n'], BK=128 (2 tiles per barrier pair,
//            R3's verified 2-barrier pattern at HALF the barrier count):
//            frags(t0) -> MFMA(t0) -> frags(t1) -> lgkm+barrier(a) -> stage next pair
//            -> MFMA(t1) covers staging -> barrier(b).
//   Epilogue: Q rows -> X2[0], K rows -> X2[1], V^T -> VTs, XOR bank-swizzled.
//   Phase B: flash attention from LDS (byte-identical to R3's best-measured version);
//            waves own group pairs {w, 15-w} (5 visits); dual-group interleave;
//            setprio around MFMA clusters.

typedef unsigned short u16;
typedef float f32x4 __attribute__((ext_vector_type(4)));
typedef short s16x8 __attribute__((ext_vector_type(8)));
typedef u16 u16x4 __attribute__((ext_vector_type(4)));

static constexpr int BB = 128;
static constexpr int TT = 256;
static constexpr int CC = 384;
static constexpr int HH = 6;
static constexpr int DD = 64;
static constexpr int MM = BB * TT;  // 32768

// ws layout (u16): WT3 [1152][384] | Xbf [M][384]
static constexpr size_t WTOFF = 0;
static constexpr size_t XOFF  = (size_t)3 * CC * CC;

// (1/sqrt(384)) * log2(e): folded into Wq so attn logits are already base-2
static constexpr float CSC = 0.07362242194579907f;

__device__ __forceinline__ u16 f2bf(float f) {
  unsigned u = __float_as_uint(f);
  u += 0x7fffu + ((u >> 16) & 1u);   // RTN-even
  return (u16)(u >> 16);
}

// async global->LDS, 16 B/lane; LDS dest = wave-uniform base + lane*16 (m104)
__device__ __forceinline__ void g2l16(const u16* g, u16* l) {
  __builtin_amdgcn_global_load_lds(
      (const __attribute__((address_space(1))) u16*)g,
      (__attribute__((address_space(3))) u16*)l, 16, 0, 0);
}

// ---------- prep: X fp32->bf16 (blocks 0..6143) + W^T via LDS transpose ----------
__global__ void prep(const float* __restrict__ X, const float* __restrict__ Wq,
                     const float* __restrict__ Wk, const float* __restrict__ Wv,
                     u16* __restrict__ ws) {
  int bx = blockIdx.x;
  if (bx < 6144) {
    size_t i = (size_t)(bx * 256 + threadIdx.x) * 8;
    f32x4 a0 = *(const f32x4*)(X + i);
    f32x4 a1 = *(const f32x4*)(X + i + 4);
    s16x8 ab;
#pragma unroll
    for (int j = 0; j < 4; ++j) { ab[j] = (short)f2bf(a0[j]); ab[4 + j] = (short)f2bf(a1[j]); }
    *(s16x8*)(ws + XOFF + i) = ab;
  } else {
    // 108 transpose blocks: z (3) x 6x6 tiles of 64x64
    __shared__ u16 Lt[64][66];
    int j = bx - 6144;
    int z = j / 36, t = j % 36, ti = t / 6, tj = t % 6;
    const float* W = (z == 0) ? Wq : (z == 1) ? Wk : Wv;
    const float sc = (z == 0) ? CSC : 1.0f;
    u16* WT = ws + WTOFF + (size_t)z * CC * CC;
    const int rl = threadIdx.x >> 4;
    const int cl = (threadIdx.x & 15) * 4;
#pragma unroll
    for (int it = 0; it < 4; ++it) {
      int r = it * 16 + rl;
      f32x4 v = *(const f32x4*)(W + (size_t)(ti * 64 + r) * CC + tj * 64 + cl);
#pragma unroll
      for (int q = 0; q < 4; ++q) Lt[r][cl + q] = f2bf(v[q] * sc);
    }
    __syncthreads();
#pragma unroll
    for (int it = 0; it < 4; ++it) {
      int n = it * 16 + rl;
      u16x4 o;
#pragma unroll
      for (int q = 0; q < 4; ++q) o[q] = Lt[cl + q][n];
      *(u16x4*)(WT + (size_t)(tj * 64 + n) * CC + ti * 64 + cl) = o;
    }
  }
}

// ---------- fused QKV projection + flash attention ----------
__global__ __launch_bounds__(512, 2) void fused(const u16* __restrict__ ws,
                                                float* __restrict__ out) {
  // XCD clustering: 6 heads of same b share ids congruent mod 8 -> same XCD L2
  const int bid = blockIdx.x;
  const int xc = bid & 7;
  const int g5 = bid >> 3;           // 0..95
  const int b = xc * 16 + g5 / 6;
  const int h = g5 % 6;

  __shared__ u16 X2[2][256][64];     // A: X tile pair; B: [0]=Q rows, [1]=K rows (swz)
  __shared__ u16 W2[2][12288];       // A: W tile pair; B: Ps (16384 u16 used)
  __shared__ u16 VTs[64][256];       // V^T, XOR-swizzled (epilogue)

  const int tid = threadIdx.x;
  const int lane = tid & 63;
  const int w = tid >> 6;            // 0..7
  const int quad = lane >> 4;
  const int col = lane & 15;

  const u16* Xg = ws + XOFF + (size_t)b * TT * CC;   // [256][384]
  const u16* Wg = ws + WTOFF;                        // [1152][384]

  const int rl = lane >> 3;          // row within 8-row staging chunk
  const int gb = (lane & 7) ^ rl;    // swizzled 8-elem block for this lane

  const int wm = (w >> 1) * 64;      // token quadrant
  const int wn = (w & 1) * 96;       // n' half (Q:0-63 K:64-127 V:128-191)

  // stage tile t (t = 0..5) into buffer t&1
  auto stage = [&](int t) {
    u16* Xd = &X2[t & 1][0][0];
    u16* Wd = &W2[t & 1][0];
#pragma unroll
    for (int i = 0; i < 4; ++i) {
      int r0 = w * 32 + i * 8;
      g2l16(Xg + (size_t)(r0 + rl) * CC + t * 64 + gb * 8, Xd + r0 * 64);
    }
#pragma unroll
    for (int i = 0; i < 3; ++i) {
      int r0 = w * 24 + i * 8;
      int rr = r0 + rl;
      int z = rr >> 6, nn = rr & 63;
      g2l16(Wg + (size_t)(z * CC + h * DD + nn) * CC + t * 64 + gb * 8,
            Wd + r0 * 64);
    }
  };

  // frag reads for tile in buffer bufi
  auto rdfrags = [&](int bufi, s16x8 (&af)[4][2], s16x8 (&bf)[6][2]) {
#pragma unroll
    for (int mt = 0; mt < 4; ++mt)
#pragma unroll
      for (int ks = 0; ks < 2; ++ks)
        af[mt][ks] = *(const s16x8*)(&X2[bufi][wm + mt * 16 + col]
                                        [(((ks * 4 + quad) ^ (col & 7)) * 8)]);
#pragma unroll
    for (int nt = 0; nt < 6; ++nt)
#pragma unroll
      for (int ks = 0; ks < 2; ++ks)
        bf[nt][ks] = *(const s16x8*)(&W2[bufi][(wn + nt * 16 + col) * 64 +
                                              (((ks * 4 + quad) ^ (col & 7)) * 8)]);
  };

  // ---------------- Phase A: BK=128, 2 barriers per 2 tiles ----------------
  f32x4 acc[4][6] = {};

  stage(0);
  stage(1);
  __syncthreads();                   // prologue: full drain + barrier

  for (int j = 0; j < 3; ++j) {
    s16x8 af[4][2], bf[6][2];

    // tile 2j (buffer 0)
    rdfrags(0, af, bf);
    __builtin_amdgcn_s_setprio(1);
#pragma unroll
    for (int ks = 0; ks < 2; ++ks)
#pragma unroll
      for (int mt = 0; mt < 4; ++mt)
#pragma unroll
        for (int nt = 0; nt < 6; ++nt)
          acc[mt][nt] = __builtin_amdgcn_mfma_f32_16x16x32_bf16(
              af[mt][ks], bf[nt][ks], acc[mt][nt], 0, 0, 0);
    __builtin_amdgcn_s_setprio(0);

    // tile 2j+1 (buffer 1) frag reads, then barrier (a): all waves done reading
    rdfrags(1, af, bf);
    __syncthreads();                 // (a) both buffers fully read by all waves

    if (j < 2) { stage(2 * j + 2); stage(2 * j + 3); }  // next pair in flight

    __builtin_amdgcn_s_setprio(1);   // MFMA(t1) covers the staging
#pragma unroll
    for (int ks = 0; ks < 2; ++ks)
#pragma unroll
      for (int mt = 0; mt < 4; ++mt)
#pragma unroll
        for (int nt = 0; nt < 6; ++nt)
          acc[mt][nt] = __builtin_amdgcn_mfma_f32_16x16x32_bf16(
              af[mt][ks], bf[nt][ks], acc[mt][nt], 0, 0, 0);
    __builtin_amdgcn_s_setprio(0);

    if (j < 2) __syncthreads();      // (b) vmcnt drained: new pair visible
  }
  // no barrier: (a) at j=2 ordered all reads before epilogue overlay writes

  // ------ Epilogue: acc -> Q(X2[0]) / K(X2[1]) rows, V^T(VTs); XOR bank-swizzle ------
  u16* Qb  = &X2[0][0][0];
  u16* KsB = &X2[1][0][0];
#pragma unroll
  for (int mt = 0; mt < 4; ++mt) {
    int tokb = wm + mt * 16 + quad * 4;
#pragma unroll
    for (int nt = 0; nt < 6; ++nt) {
      int gn = wn + nt * 16 + col;           // class uniform per (w,nt)
      if (gn < 128) {
        u16* dst = (gn < 64) ? Qb : KsB;
        int d = gn & 63;
#pragma unroll
        for (int r = 0; r < 4; ++r) {
          int tok = tokb + r;
          dst[tok * 64 + (d ^ ((tok & 7) << 3))] = f2bf(acc[mt][nt][r]);
        }
      } else {
        int d = gn - 128;
        uint2 pk;
        pk.x = (unsigned)f2bf(acc[mt][nt][0]) | ((unsigned)f2bf(acc[mt][nt][1]) << 16);
        pk.y = (unsigned)f2bf(acc[mt][nt][2]) | ((unsigned)f2bf(acc[mt][nt][3]) << 16);
        *(uint2*)((u16*)VTs + d * 256 + (tokb ^ ((d & 15) << 3))) = pk;
      }
    }
  }
  __syncthreads();

  // ---------------- Phase B: flash attention from LDS, barrier-free ----------------
  const int g0 = w, g1 = 15 - w;             // this wave's two q-groups
  const int k0max = g0 >> 2, k1max = g1 >> 2;
  const int qq0 = (g0 & 3) * 16 + col;
  const int qq1 = (g1 & 3) * 16 + col;
  u16* PsA = &W2[0][0] + w * 2048;           // per-wave [16][64] swizzled
  u16* PsB = PsA + 1024;

  s16x8 qf[2][2];
  {
    int qr0 = g0 * 16 + col, qr1 = g1 * 16 + col;
#pragma unroll
    for (int ks = 0; ks < 2; ++ks) {
      qf[0][ks] = *(const s16x8*)(Qb + qr0 * 64 + (((ks * 4 + quad) ^ (col & 7)) * 8));
      qf[1][ks] = *(const s16x8*)(Qb + qr1 * 64 + (((ks * 4 + quad) ^ (col & 7)) * 8));
    }
  }

  f32x4 o[2][4] = {};
  float mst[2] = {-1.0e30f, -1.0e30f}, lst[2] = {0.0f, 0.0f};

  // softmax step: mask (if diag), row-max, rescale state, exp, pack to bf16 pairs
  auto sm = [&](f32x4 (&s)[4], bool diag, int qq, float& m, float& l,
                unsigned (&pk)[4][2]) -> float {
    float rmax = -1.0e30f;
#pragma unroll
    for (int nt = 0; nt < 4; ++nt)
#pragma unroll
      for (int r = 0; r < 4; ++r) {
        float t = s[nt][r];
        if (diag && (nt * 16 + quad * 4 + r) > qq) t = -1.0e30f;
        s[nt][r] = t;
        rmax = fmaxf(rmax, t);
      }
    rmax = fmaxf(rmax, __shfl_xor(rmax, 16));
    rmax = fmaxf(rmax, __shfl_xor(rmax, 32));
    float mn = fmaxf(m, rmax);
    float alpha = exp2f(m - mn);
    m = mn;
    float lsum = 0.0f;
#pragma unroll
    for (int nt = 0; nt < 4; ++nt) {
      float p0 = exp2f(s[nt][0] - mn), p1 = exp2f(s[nt][1] - mn);
      float p2 = exp2f(s[nt][2] - mn), p3 = exp2f(s[nt][3] - mn);
      lsum += (p0 + p1) + (p2 + p3);
      pk[nt][0] = (unsigned)f2bf(p0) | ((unsigned)f2bf(p1) << 16);
      pk[nt][1] = (unsigned)f2bf(p2) | ((unsigned)f2bf(p3) << 16);
    }
    l = l * alpha + lsum;
    return alpha;
  };

  for (int kt = 0; kt <= k1max; ++kt) {
    const bool both = (kt <= k0max);         // wave-uniform

    s16x8 kf[4][2], vf[4][2];
#pragma unroll
    for (int nt = 0; nt < 4; ++nt)
#pragma unroll
      for (int ks = 0; ks < 2; ++ks) {
        int key = kt * 64 + nt * 16 + col;
        kf[nt][ks] = *(const s16x8*)(KsB + key * 64 +
                                     (((ks * 4 + quad) ^ (col & 7)) * 8));
        int d = nt * 16 + col;
        vf[nt][ks] = *(const s16x8*)((const u16*)VTs + d * 256 +
                     ((kt * 64 + ks * 32 + quad * 8) ^ ((d & 15) << 3)));
      }

    // QK^T both groups back-to-back (independent MFMA chains fill the pipe)
    f32x4 sA[4] = {}, sB[4] = {};
    __builtin_amdgcn_s_setprio(1);
    if (both) {
#pragma unroll
      for (int ks = 0; ks < 2; ++ks)
#pragma unroll
        for (int nt = 0; nt < 4; ++nt)
          sA[nt] = __builtin_amdgcn_mfma_f32_16x16x32_bf16(kf[nt][ks], qf[0][ks],
                                                           sA[nt], 0, 0, 0);
    }
#pragma unroll
    for (int ks = 0; ks < 2; ++ks)
#pragma unroll
      for (int nt = 0; nt < 4; ++nt)
        sB[nt] = __builtin_amdgcn_mfma_f32_16x16x32_bf16(kf[nt][ks], qf[1][ks],
                                                         sB[nt], 0, 0, 0);
    __builtin_amdgcn_s_setprio(0);

    unsigned pkA[4][2], pkB[4][2];
    float aA = 1.0f, aB;
    if (both) {
      aA = sm(sA, kt == k0max, qq0, mst[0], lst[0], pkA);
#pragma unroll
      for (int nt = 0; nt < 4; ++nt)
        *(uint2*)(PsA + col * 64 + ((nt * 16 + quad * 4) ^ ((col & 7) << 3))) =
            make_uint2(pkA[nt][0], pkA[nt][1]);
    }
    aB = sm(sB, kt == k1max, qq1, mst[1], lst[1], pkB);
#pragma unroll
    for (int nt = 0; nt < 4; ++nt)
      *(uint2*)(PsB + col * 64 + ((nt * 16 + quad * 4) ^ ((col & 7) << 3))) =
          make_uint2(pkB[nt][0], pkB[nt][1]);

    // O-rescales overlap the ds_write latency
    if (both) {
#pragma unroll
      for (int dt = 0; dt < 4; ++dt)
#pragma unroll
        for (int r = 0; r < 4; ++r) o[0][dt][r] *= aA;
    }
#pragma unroll
    for (int dt = 0; dt < 4; ++dt)
#pragma unroll
      for (int r = 0; r < 4; ++r) o[1][dt][r] *= aB;

    asm volatile("s_waitcnt lgkmcnt(0)" ::: "memory");  // P writes visible (own wave)

    s16x8 pfA[2], pfB[2];
    if (both) {
#pragma unroll
      for (int ks = 0; ks < 2; ++ks)
        pfA[ks] = *(const s16x8*)(PsA + col * 64 +
                                  ((ks * 32 + quad * 8) ^ ((col & 7) << 3)));
    }
#pragma unroll
    for (int ks = 0; ks < 2; ++ks)
      pfB[ks] = *(const s16x8*)(PsB + col * 64 +
                                ((ks * 32 + quad * 8) ^ ((col & 7) << 3)));

    __builtin_amdgcn_s_setprio(1);
    if (both) {
#pragma unroll
      for (int ks = 0; ks < 2; ++ks)
#pragma unroll
        for (int dt = 0; dt < 4; ++dt)
          o[0][dt] = __builtin_amdgcn_mfma_f32_16x16x32_bf16(vf[dt][ks], pfA[ks],
                                                             o[0][dt], 0, 0, 0);
    }
#pragma unroll
    for (int ks = 0; ks < 2; ++ks)
#pragma unroll
      for (int dt = 0; dt < 4; ++dt)
        o[1][dt] = __builtin_amdgcn_mfma_f32_16x16x32_bf16(vf[dt][ks], pfB[ks],
                                                           o[1][dt], 0, 0, 0);
    __builtin_amdgcn_s_setprio(0);
  }

  // epilogue: O^T row = d = dt*16+quad*4+r, col = q -> out[b,q,h*64+d]
#pragma unroll
  for (int gi = 0; gi < 2; ++gi) {
    int g = gi ? g1 : g0;
    float l = lst[gi];
    l += __shfl_xor(l, 16);
    l += __shfl_xor(l, 32);
    float inv = 1.0f / l;
    int q = g * 16 + col;
#pragma unroll
    for (int dt = 0; dt < 4; ++dt) {
      f32x4 res;
#pragma unroll
      for (int r = 0; r < 4; ++r) res[r] = o[gi][dt][r] * inv;
      *(f32x4*)(out + (size_t)(b * TT + q) * CC + h * DD + dt * 16 + quad * 4) = res;
    }
  }
}

extern "C" void kernel_launch(void* const* d_in, const int* in_sizes, int n_in,
                              void* d_out, int out_size, void* d_ws, size_t ws_size,
                              hipStream_t stream) {
  const float* x  = (const float*)d_in[0];
  const float* wq = (const float*)d_in[1];
  const float* wk = (const float*)d_in[2];
  const float* wv = (const float*)d_in[3];
  u16* ws  = (u16*)d_ws;
  float* out = (float*)d_out;

  prep<<<dim3(6144 + 108), 256, 0, stream>>>(x, wq, wk, wv, ws);
  fused<<<dim3(BB * HH), 512, 0, stream>>>(ws, out);
}